// Round 12
// baseline (240.284 us; speedup 1.0000x reference)
//
#include <hip/hip_runtime.h>
#include <hip/hip_bf16.h>

// Problem: B=8, T=4096, D=64, K=1024. N = B*T = 32768 rows.
// Inputs:  d_in[0] = x (f32, 2097152), d_in[1] = embeddings (f32, [D][K])
// Output (f32): quantized (2097152) | encodings (33554432) | indices (32768) | loss (1)
//
// Score s[n,k] = x_n.e_k - 0.5||e_k||^2 (argmax == argmin distance).
// Split-fp16 3-MFMA coarse scores (err ~1e-4); rows with top2-gap <= MARGIN
// rescanned exactly in f32 inside the same block. One fused main kernel,
// shaped for the write stream: 2048 blocks x 256 thr (32 waves/CU).

#define NROWS 32768
#define DDIM  64
#define KCB   1024
#define MARGIN 0.02f

typedef float    f32x4 __attribute__((ext_vector_type(4)));
typedef _Float16 f16x8 __attribute__((ext_vector_type(8)));

// ws layout (f32 index):
#define WS_ET    0         // Et f32 [k][64]             (65536)
#define WS_H     65536     // 0.5*||e_k||^2              (1024)
#define WS_PART  66560     // loss partials              (2048)
#define WS_EHI   68608     // E hi fp16 permuted [k][64] (32768 f32 slots)
#define WS_ELO   101376    // E lo fp16 permuted [k][64] (32768 f32 slots)
// end: 134144 f32 = 537 KB

// K_A: Et f32 [k][d]; permuted split-fp16 Ehi/Elo (packed 16-B stores); h.
// slot p (0..31) of window w holds d = w*32 + 4*(p>>3) + (p&3) + 16*((p>>2)&1).
__global__ __launch_bounds__(64) void kA_prep(const float* __restrict__ E,
                                              float* __restrict__ Et,
                                              float* __restrict__ h,
                                              _Float16* __restrict__ Ehi,
                                              _Float16* __restrict__ Elo) {
  int k = blockIdx.x * 64 + threadIdx.x;    // 0..1023
  float col[DDIM];
  float sum = 0.f;
#pragma unroll
  for (int d = 0; d < DDIM; ++d) {
    float v = E[d * KCB + k];               // coalesced across lanes
    col[d] = v;
    sum = fmaf(v, v, sum);
  }
  float4* dst = (float4*)(Et + (size_t)k * DDIM);
#pragma unroll
  for (int i = 0; i < 16; ++i)
    dst[i] = make_float4(col[4*i], col[4*i+1], col[4*i+2], col[4*i+3]);
  h[k] = 0.5f * sum;

#pragma unroll
  for (int w = 0; w < 2; ++w) {
    f16x8 hi8[4], lo8[4];
#pragma unroll
    for (int p = 0; p < 32; ++p) {
      int dl = w * 32 + 4 * (p >> 3) + (p & 3) + 16 * ((p >> 2) & 1);
      float v = col[dl];
      _Float16 hi = (_Float16)v;
      hi8[p >> 3][p & 7] = hi;
      lo8[p >> 3][p & 7] = (_Float16)(v - (float)hi);
    }
#pragma unroll
    for (int q = 0; q < 4; ++q) {
      *(f16x8*)(Ehi + (size_t)k * DDIM + w * 32 + q * 8) = hi8[q];
      *(f16x8*)(Elo + (size_t)k * DDIM + w * 32 + q * 8) = lo8[q];
    }
  }
}

// K_B: fused main. Block = 256 thr (4 waves) = 16 rows; wave wq scores the
// 256-code quarter [wq*256, wq*256+256) with the r10-verified MFMA flow.
__global__ __launch_bounds__(256, 8) void kB_main(const float* __restrict__ x,
                                                  const _Float16* __restrict__ Ehi,
                                                  const _Float16* __restrict__ Elo,
                                                  const float* __restrict__ Et,
                                                  const float* __restrict__ h,
                                                  float* __restrict__ partial,
                                                  float* __restrict__ out_q,
                                                  float* __restrict__ out_enc,
                                                  float* __restrict__ out_ind) {
  __shared__ float mb1[4][16], mb2[4][16];
  __shared__ int   mi1[4][16];
  __shared__ int   sidx[16];
  __shared__ int   flags[16];
  __shared__ int   nflag;
  __shared__ float rbw[4];
  __shared__ int   riw[4];
  __shared__ float red[4];

  int tid  = threadIdx.x;
  int wq   = tid >> 6;               // wave -> code quarter
  int lane = tid & 63;
  int g = lane >> 4, c = lane & 15;
  int r0 = blockIdx.x * 16;

  if (tid == 0) nflag = 0;

  // A-fragments for row r0 + c; slots (g,e): d = w*32 + 4g + (e&3) + 16*(e>>2)
  f16x8 Ahi[2], Alo[2];
  {
    const float* xb = x + (size_t)(r0 + c) * DDIM;
#pragma unroll
    for (int w = 0; w < 2; ++w) {
      f32x4 xa = *(const f32x4*)(xb + w * 32 + 4 * g);
      f32x4 xc = *(const f32x4*)(xb + w * 32 + 16 + 4 * g);
#pragma unroll
      for (int e = 0; e < 4; ++e) {
        _Float16 hi = (_Float16)xa[e];
        Ahi[w][e] = hi;
        Alo[w][e] = (_Float16)(xa[e] - (float)hi);
      }
#pragma unroll
      for (int e = 0; e < 4; ++e) {
        _Float16 hi = (_Float16)xc[e];
        Ahi[w][4 + e] = hi;
        Alo[w][4 + e] = (_Float16)(xc[e] - (float)hi);
      }
    }
  }

  float b1[4], b2[4];
  int   i1[4];
#pragma unroll
  for (int q = 0; q < 4; ++q) { b1[q] = -3.0e38f; b2[q] = -3.0e38f; i1[q] = 0; }

  const _Float16* peh = Ehi + (size_t)(wq * 256 + c) * DDIM + g * 8;
  const _Float16* pel = Elo + (size_t)(wq * 256 + c) * DDIM + g * 8;

#pragma unroll 1
  for (int ch = 0; ch < 16; ++ch) {
    size_t off = (size_t)ch * 16 * DDIM;
    f16x8 bh0 = *(const f16x8*)(peh + off);
    f16x8 bl0 = *(const f16x8*)(pel + off);
    f16x8 bh1 = *(const f16x8*)(peh + off + 32);
    f16x8 bl1 = *(const f16x8*)(pel + off + 32);
    float hc = h[wq * 256 + ch * 16 + c];
    int code = wq * 256 + ch * 16 + c;
    f32x4 a = { -hc, -hc, -hc, -hc };
    a = __builtin_amdgcn_mfma_f32_16x16x32_f16(Alo[0], bh0, a, 0, 0, 0);
    a = __builtin_amdgcn_mfma_f32_16x16x32_f16(Ahi[0], bl0, a, 0, 0, 0);
    a = __builtin_amdgcn_mfma_f32_16x16x32_f16(Ahi[0], bh0, a, 0, 0, 0);
    a = __builtin_amdgcn_mfma_f32_16x16x32_f16(Alo[1], bh1, a, 0, 0, 0);
    a = __builtin_amdgcn_mfma_f32_16x16x32_f16(Ahi[1], bl1, a, 0, 0, 0);
    a = __builtin_amdgcn_mfma_f32_16x16x32_f16(Ahi[1], bh1, a, 0, 0, 0);
#pragma unroll
    for (int q = 0; q < 4; ++q) {
      float s = a[q];
      bool gt = s > b1[q];
      b2[q] = gt ? b1[q] : fmaxf(b2[q], s);
      i1[q] = gt ? code : i1[q];
      b1[q] = gt ? s : b1[q];
    }
  }

  // reduce across the 16 code-lanes (same g), lex tie-break to smaller index
#pragma unroll
  for (int step = 1; step <= 8; step <<= 1) {
#pragma unroll
    for (int q = 0; q < 4; ++q) {
      float ob1 = __shfl_xor(b1[q], step);
      int   oi1 = __shfl_xor(i1[q], step);
      float ob2 = __shfl_xor(b2[q], step);
      bool win = (ob1 > b1[q]) || (ob1 == b1[q] && oi1 < i1[q]);
      float loser = win ? b1[q] : ob1;
      b1[q] = win ? ob1 : b1[q];
      i1[q] = win ? oi1 : i1[q];
      b2[q] = fmaxf(fmaxf(b2[q], ob2), loser);
    }
  }
  if (c == 0) {
#pragma unroll
    for (int q = 0; q < 4; ++q) {
      int row = 4 * g + q;            // 0..15
      mb1[wq][row] = b1[q];
      mi1[wq][row] = i1[q];
      mb2[wq][row] = b2[q];
    }
  }
  __syncthreads();

  // merge the 4 quarters (ascending -> first-occurrence ties); flag near-ties
  if (tid < 16) {
    float bb1 = mb1[0][tid], bb2 = mb2[0][tid];
    int   ii1 = mi1[0][tid];
#pragma unroll
    for (int qd = 1; qd < 4; ++qd) {
      float a1 = mb1[qd][tid];
      int   j1 = mi1[qd][tid];
      bool w1 = (a1 > bb1) || (a1 == bb1 && j1 < ii1);
      bb2 = fmaxf(fmaxf(bb2, mb2[qd][tid]), w1 ? bb1 : a1);
      bb1 = w1 ? a1 : bb1;
      ii1 = w1 ? j1 : ii1;
    }
    sidx[tid] = ii1;
    if (bb1 - bb2 <= MARGIN) { int p = atomicAdd(&nflag, 1); flags[p] = tid; }
  }
  __syncthreads();

  // exact f32 rescan of flagged rows (rare), whole block per row
  int nf = nflag;
#pragma unroll 1
  for (int fi = 0; fi < nf; ++fi) {
    int row = flags[fi];
    int n = r0 + row;
    float best = -3.0e38f; int bi = 0;
#pragma unroll 1
    for (int j = 0; j < 4; ++j) {
      int code = j * 256 + tid;
      const f32x4* er = (const f32x4*)(Et + (size_t)code * DDIM);
      const f32x4* xr = (const f32x4*)(x + (size_t)n * DDIM);   // L1-resident broadcast
      float acc = -h[code];
#pragma unroll
      for (int d = 0; d < 16; ++d) {
        f32x4 e4 = er[d], x4 = xr[d];
        acc = fmaf(x4[0], e4[0], acc); acc = fmaf(x4[1], e4[1], acc);
        acc = fmaf(x4[2], e4[2], acc); acc = fmaf(x4[3], e4[3], acc);
      }
      if (acc > best || (acc == best && code < bi)) { best = acc; bi = code; }
    }
#pragma unroll
    for (int step = 1; step <= 32; step <<= 1) {
      float ob = __shfl_xor(best, step);
      int   oi = __shfl_xor(bi, step);
      if (ob > best || (ob == best && oi < bi)) { best = ob; bi = oi; }
    }
    if (lane == 0) { rbw[wq] = best; riw[wq] = bi; }
    __syncthreads();
    if (tid == 0) {
      float bb = rbw[0]; int ii = riw[0];
#pragma unroll
      for (int qd = 1; qd < 4; ++qd) {
        bool w1 = (rbw[qd] > bb) || (rbw[qd] == bb && riw[qd] < ii);
        bb = w1 ? rbw[qd] : bb;
        ii = w1 ? riw[qd] : ii;
      }
      sidx[row] = ii;
    }
    __syncthreads();
  }

  // ---- outputs ----
  if (tid < 16) out_ind[r0 + tid] = (float)sidx[tid];

  // quantized + loss: 256 f32x4 chunks, 1 per thread (16 rows x 16 chunks)
  float lsum;
  {
    int row = tid >> 4, cc = tid & 15;
    int n = r0 + row;
    int bi = sidx[row];
    f32x4 q4 = *(const f32x4*)(Et + (size_t)bi * DDIM + cc * 4);
    f32x4 x4 = *(const f32x4*)(x + (size_t)n * DDIM + cc * 4);
    float d0 = q4[0] - x4[0], d1 = q4[1] - x4[1], d2 = q4[2] - x4[2], d3 = q4[3] - x4[3];
    lsum = d0 * d0;
    lsum = fmaf(d1, d1, lsum); lsum = fmaf(d2, d2, lsum); lsum = fmaf(d3, d3, lsum);
    __builtin_nontemporal_store(q4, (f32x4*)(out_q + (size_t)n * DDIM + cc * 4));
  }

  // one-hot encodings: per row 256 f32x4 over 256 threads (1 each), 16 rows
#pragma unroll 1
  for (int rr = 0; rr < 16; ++rr) {
    int bk = sidx[rr];
    f32x4 v = (f32x4)(0.f);
    if ((bk >> 2) == tid) v[bk & 3] = 1.0f;
    __builtin_nontemporal_store(v, (f32x4*)(out_enc + (size_t)(r0 + rr) * KCB + tid * 4));
  }

  // loss partial: shfl within wave -> LDS -> plain store
#pragma unroll
  for (int off = 32; off > 0; off >>= 1) lsum += __shfl_down(lsum, off);
  if (lane == 0) red[wq] = lsum;
  __syncthreads();
  if (tid == 0) partial[blockIdx.x] = red[0] + red[1] + red[2] + red[3];
}

// K5: reduce 2048 partials -> loss.
__global__ void k5_loss(const float* __restrict__ partial, float* __restrict__ out_loss) {
  int t = threadIdx.x;                 // 256 threads
  float s = 0.f;
#pragma unroll
  for (int i = 0; i < 8; ++i) s += partial[t + i * 256];
#pragma unroll
  for (int off = 32; off > 0; off >>= 1) s += __shfl_down(s, off);
  __shared__ float red[4];
  int lane = t & 63, w = t >> 6;
  if (lane == 0) red[w] = s;
  __syncthreads();
  if (t == 0) out_loss[0] = (red[0] + red[1] + red[2] + red[3]) * (1.0f / 2097152.0f);
}

extern "C" void kernel_launch(void* const* d_in, const int* in_sizes, int n_in,
                              void* d_out, int out_size, void* d_ws, size_t ws_size,
                              hipStream_t stream) {
  const float* x = (const float*)d_in[0];
  const float* E = (const float*)d_in[1];

  float* ws   = (float*)d_ws;
  float* Et   = ws + WS_ET;
  float* h    = ws + WS_H;
  float* part = ws + WS_PART;
  _Float16* Ehi = (_Float16*)(ws + WS_EHI);
  _Float16* Elo = (_Float16*)(ws + WS_ELO);

  float* out      = (float*)d_out;
  float* out_q    = out;                      // 2097152
  float* out_enc  = out + 2097152;            // 33554432
  float* out_ind  = out + 35651584;           // 32768
  float* out_loss = out + 35684352;           // 1

  kA_prep<<<16, 64, 0, stream>>>(E, Et, h, Ehi, Elo);
  kB_main<<<2048, 256, 0, stream>>>(x, Ehi, Elo, Et, h, part, out_q, out_enc, out_ind);
  k5_loss<<<1, 256, 0, stream>>>(part, out_loss);
}

// Round 13
// 233.973 us; speedup vs baseline: 1.0270x; 1.0270x over previous
//
#include <hip/hip_runtime.h>
#include <hip/hip_bf16.h>

// Problem: B=8, T=4096, D=64, K=1024. N = B*T = 32768 rows.
// Inputs:  d_in[0] = x (f32, 2097152), d_in[1] = embeddings (f32, [D][K])
// Output (f32): quantized (2097152) | encodings (33554432) | indices (32768) | loss (1)
//
// Score s[n,k] = x_n.e_k - 0.5||e_k||^2 (argmax == argmin distance).
// Split-fp16 3-MFMA coarse scores (err ~1e-4); rows with top2-gap <= MARGIN
// rescanned exactly in f32 inside the same block. One fused main kernel.
// r13 fixes: launch_bounds(256,4) [r12's (256,8) forced VGPR=32 -> remat storm],
// register-prefetch of E fragments restored, plain (non-nt) output stores.

#define NROWS 32768
#define DDIM  64
#define KCB   1024
#define MARGIN 0.02f

typedef float    f32x4 __attribute__((ext_vector_type(4)));
typedef _Float16 f16x8 __attribute__((ext_vector_type(8)));

// ws layout (f32 index):
#define WS_ET    0         // Et f32 [k][64]             (65536)
#define WS_H     65536     // 0.5*||e_k||^2              (1024)
#define WS_PART  66560     // loss partials              (2048)
#define WS_EHI   68608     // E hi fp16 permuted [k][64] (32768 f32 slots)
#define WS_ELO   101376    // E lo fp16 permuted [k][64] (32768 f32 slots)
// end: 134144 f32 = 537 KB

// K_A: Et f32 [k][d]; permuted split-fp16 Ehi/Elo (packed 16-B stores); h.
// slot p (0..31) of window w holds d = w*32 + 4*(p>>3) + (p&3) + 16*((p>>2)&1).
__global__ __launch_bounds__(64) void kA_prep(const float* __restrict__ E,
                                              float* __restrict__ Et,
                                              float* __restrict__ h,
                                              _Float16* __restrict__ Ehi,
                                              _Float16* __restrict__ Elo) {
  int k = blockIdx.x * 64 + threadIdx.x;    // 0..1023
  float col[DDIM];
  float sum = 0.f;
#pragma unroll
  for (int d = 0; d < DDIM; ++d) {
    float v = E[d * KCB + k];               // coalesced across lanes
    col[d] = v;
    sum = fmaf(v, v, sum);
  }
  float4* dst = (float4*)(Et + (size_t)k * DDIM);
#pragma unroll
  for (int i = 0; i < 16; ++i)
    dst[i] = make_float4(col[4*i], col[4*i+1], col[4*i+2], col[4*i+3]);
  h[k] = 0.5f * sum;

#pragma unroll
  for (int w = 0; w < 2; ++w) {
    f16x8 hi8[4], lo8[4];
#pragma unroll
    for (int p = 0; p < 32; ++p) {
      int dl = w * 32 + 4 * (p >> 3) + (p & 3) + 16 * ((p >> 2) & 1);
      float v = col[dl];
      _Float16 hi = (_Float16)v;
      hi8[p >> 3][p & 7] = hi;
      lo8[p >> 3][p & 7] = (_Float16)(v - (float)hi);
    }
#pragma unroll
    for (int q = 0; q < 4; ++q) {
      *(f16x8*)(Ehi + (size_t)k * DDIM + w * 32 + q * 8) = hi8[q];
      *(f16x8*)(Elo + (size_t)k * DDIM + w * 32 + q * 8) = lo8[q];
    }
  }
}

// K_B: fused main. Block = 256 thr (4 waves) = 16 rows; wave wq scores the
// 256-code quarter [wq*256, wq*256+256) with the r10-verified MFMA flow.
__global__ __launch_bounds__(256, 4) void kB_main(const float* __restrict__ x,
                                                  const _Float16* __restrict__ Ehi,
                                                  const _Float16* __restrict__ Elo,
                                                  const float* __restrict__ Et,
                                                  const float* __restrict__ h,
                                                  float* __restrict__ partial,
                                                  float* __restrict__ out_q,
                                                  float* __restrict__ out_enc,
                                                  float* __restrict__ out_ind) {
  __shared__ float mb1[4][16], mb2[4][16];
  __shared__ int   mi1[4][16];
  __shared__ int   sidx[16];
  __shared__ int   flags[16];
  __shared__ int   nflag;
  __shared__ float rbw[4];
  __shared__ int   riw[4];
  __shared__ float red[4];

  int tid  = threadIdx.x;
  int wq   = tid >> 6;               // wave -> code quarter
  int lane = tid & 63;
  int g = lane >> 4, c = lane & 15;
  int r0 = blockIdx.x * 16;

  if (tid == 0) nflag = 0;

  // A-fragments for row r0 + c; slots (g,e): d = w*32 + 4g + (e&3) + 16*(e>>2)
  f16x8 Ahi[2], Alo[2];
  {
    const float* xb = x + (size_t)(r0 + c) * DDIM;
#pragma unroll
    for (int w = 0; w < 2; ++w) {
      f32x4 xa = *(const f32x4*)(xb + w * 32 + 4 * g);
      f32x4 xc = *(const f32x4*)(xb + w * 32 + 16 + 4 * g);
#pragma unroll
      for (int e = 0; e < 4; ++e) {
        _Float16 hi = (_Float16)xa[e];
        Ahi[w][e] = hi;
        Alo[w][e] = (_Float16)(xa[e] - (float)hi);
      }
#pragma unroll
      for (int e = 0; e < 4; ++e) {
        _Float16 hi = (_Float16)xc[e];
        Ahi[w][4 + e] = hi;
        Alo[w][4 + e] = (_Float16)(xc[e] - (float)hi);
      }
    }
  }

  float b1[4], b2[4];
  int   i1[4];
#pragma unroll
  for (int q = 0; q < 4; ++q) { b1[q] = -3.0e38f; b2[q] = -3.0e38f; i1[q] = 0; }

  const _Float16* peh = Ehi + (size_t)(wq * 256 + c) * DDIM + g * 8;
  const _Float16* pel = Elo + (size_t)(wq * 256 + c) * DDIM + g * 8;

  // register double-buffer prefetch (r10/r11-verified)
  f16x8 bh0n = *(const f16x8*)(peh);
  f16x8 bl0n = *(const f16x8*)(pel);
  f16x8 bh1n = *(const f16x8*)(peh + 32);
  f16x8 bl1n = *(const f16x8*)(pel + 32);
  float hn = h[wq * 256 + c];

#pragma unroll 1
  for (int ch = 0; ch < 16; ++ch) {
    f16x8 bh0 = bh0n, bl0 = bl0n, bh1 = bh1n, bl1 = bl1n;
    float hc = hn;
    if (ch < 15) {
      size_t off = (size_t)(ch + 1) * 16 * DDIM;
      bh0n = *(const f16x8*)(peh + off);
      bl0n = *(const f16x8*)(pel + off);
      bh1n = *(const f16x8*)(peh + off + 32);
      bl1n = *(const f16x8*)(pel + off + 32);
      hn = h[wq * 256 + (ch + 1) * 16 + c];
    }
    int code = wq * 256 + ch * 16 + c;
    f32x4 a = { -hc, -hc, -hc, -hc };
    a = __builtin_amdgcn_mfma_f32_16x16x32_f16(Alo[0], bh0, a, 0, 0, 0);
    a = __builtin_amdgcn_mfma_f32_16x16x32_f16(Ahi[0], bl0, a, 0, 0, 0);
    a = __builtin_amdgcn_mfma_f32_16x16x32_f16(Ahi[0], bh0, a, 0, 0, 0);
    a = __builtin_amdgcn_mfma_f32_16x16x32_f16(Alo[1], bh1, a, 0, 0, 0);
    a = __builtin_amdgcn_mfma_f32_16x16x32_f16(Ahi[1], bl1, a, 0, 0, 0);
    a = __builtin_amdgcn_mfma_f32_16x16x32_f16(Ahi[1], bh1, a, 0, 0, 0);
#pragma unroll
    for (int q = 0; q < 4; ++q) {
      float s = a[q];
      bool gt = s > b1[q];
      b2[q] = gt ? b1[q] : fmaxf(b2[q], s);
      i1[q] = gt ? code : i1[q];
      b1[q] = gt ? s : b1[q];
    }
  }

  // reduce across the 16 code-lanes (same g), lex tie-break to smaller index
#pragma unroll
  for (int step = 1; step <= 8; step <<= 1) {
#pragma unroll
    for (int q = 0; q < 4; ++q) {
      float ob1 = __shfl_xor(b1[q], step);
      int   oi1 = __shfl_xor(i1[q], step);
      float ob2 = __shfl_xor(b2[q], step);
      bool win = (ob1 > b1[q]) || (ob1 == b1[q] && oi1 < i1[q]);
      float loser = win ? b1[q] : ob1;
      b1[q] = win ? ob1 : b1[q];
      i1[q] = win ? oi1 : i1[q];
      b2[q] = fmaxf(fmaxf(b2[q], ob2), loser);
    }
  }
  if (c == 0) {
#pragma unroll
    for (int q = 0; q < 4; ++q) {
      int row = 4 * g + q;            // 0..15
      mb1[wq][row] = b1[q];
      mi1[wq][row] = i1[q];
      mb2[wq][row] = b2[q];
    }
  }
  __syncthreads();

  // merge the 4 quarters (ascending -> first-occurrence ties); flag near-ties
  if (tid < 16) {
    float bb1 = mb1[0][tid], bb2 = mb2[0][tid];
    int   ii1 = mi1[0][tid];
#pragma unroll
    for (int qd = 1; qd < 4; ++qd) {
      float a1 = mb1[qd][tid];
      int   j1 = mi1[qd][tid];
      bool w1 = (a1 > bb1) || (a1 == bb1 && j1 < ii1);
      bb2 = fmaxf(fmaxf(bb2, mb2[qd][tid]), w1 ? bb1 : a1);
      bb1 = w1 ? a1 : bb1;
      ii1 = w1 ? j1 : ii1;
    }
    sidx[tid] = ii1;
    if (bb1 - bb2 <= MARGIN) { int p = atomicAdd(&nflag, 1); flags[p] = tid; }
  }
  __syncthreads();

  // exact f32 rescan of flagged rows (rare), whole block per row
  int nf = nflag;
#pragma unroll 1
  for (int fi = 0; fi < nf; ++fi) {
    int row = flags[fi];
    int n = r0 + row;
    const f32x4* xr = (const f32x4*)(x + (size_t)n * DDIM);   // L1-resident broadcast
    float best = -3.0e38f; int bi = 0;
#pragma unroll 1
    for (int j = 0; j < 4; ++j) {
      int code = j * 256 + tid;
      const f32x4* er = (const f32x4*)(Et + (size_t)code * DDIM);
      float acc = -h[code];
#pragma unroll
      for (int d = 0; d < 16; ++d) {
        f32x4 e4 = er[d], x4 = xr[d];
        acc = fmaf(x4[0], e4[0], acc); acc = fmaf(x4[1], e4[1], acc);
        acc = fmaf(x4[2], e4[2], acc); acc = fmaf(x4[3], e4[3], acc);
      }
      if (acc > best || (acc == best && code < bi)) { best = acc; bi = code; }
    }
#pragma unroll
    for (int step = 1; step <= 32; step <<= 1) {
      float ob = __shfl_xor(best, step);
      int   oi = __shfl_xor(bi, step);
      if (ob > best || (ob == best && oi < bi)) { best = ob; bi = oi; }
    }
    if (lane == 0) { rbw[wq] = best; riw[wq] = bi; }
    __syncthreads();
    if (tid == 0) {
      float bb = rbw[0]; int ii = riw[0];
#pragma unroll
      for (int qd = 1; qd < 4; ++qd) {
        bool w1 = (rbw[qd] > bb) || (rbw[qd] == bb && riw[qd] < ii);
        bb = w1 ? rbw[qd] : bb;
        ii = w1 ? riw[qd] : ii;
      }
      sidx[row] = ii;
    }
    __syncthreads();
  }

  // ---- outputs (plain stores; fill kernel proves plain streaming = 6.4 TB/s) ----
  if (tid < 16) out_ind[r0 + tid] = (float)sidx[tid];

  // quantized + loss: 256 f32x4 chunks, 1 per thread (16 rows x 16 chunks)
  float lsum;
  {
    int row = tid >> 4, cc = tid & 15;
    int n = r0 + row;
    int bi = sidx[row];
    f32x4 q4 = *(const f32x4*)(Et + (size_t)bi * DDIM + cc * 4);
    f32x4 x4 = *(const f32x4*)(x + (size_t)n * DDIM + cc * 4);
    float d0 = q4[0] - x4[0], d1 = q4[1] - x4[1], d2 = q4[2] - x4[2], d3 = q4[3] - x4[3];
    lsum = d0 * d0;
    lsum = fmaf(d1, d1, lsum); lsum = fmaf(d2, d2, lsum); lsum = fmaf(d3, d3, lsum);
    *(f32x4*)(out_q + (size_t)n * DDIM + cc * 4) = q4;
  }

  // one-hot encodings: per row 256 f32x4 over 256 threads (1 each), 16 rows
#pragma unroll 1
  for (int rr = 0; rr < 16; ++rr) {
    int bk = sidx[rr];
    f32x4 v = (f32x4)(0.f);
    if ((bk >> 2) == tid) v[bk & 3] = 1.0f;
    *(f32x4*)(out_enc + (size_t)(r0 + rr) * KCB + tid * 4) = v;
  }

  // loss partial: shfl within wave -> LDS -> plain store
#pragma unroll
  for (int off = 32; off > 0; off >>= 1) lsum += __shfl_down(lsum, off);
  if (lane == 0) red[wq] = lsum;
  __syncthreads();
  if (tid == 0) partial[blockIdx.x] = red[0] + red[1] + red[2] + red[3];
}

// K5: reduce 2048 partials -> loss.
__global__ void k5_loss(const float* __restrict__ partial, float* __restrict__ out_loss) {
  int t = threadIdx.x;                 // 256 threads
  float s = 0.f;
#pragma unroll
  for (int i = 0; i < 8; ++i) s += partial[t + i * 256];
#pragma unroll
  for (int off = 32; off > 0; off >>= 1) s += __shfl_down(s, off);
  __shared__ float red[4];
  int lane = t & 63, w = t >> 6;
  if (lane == 0) red[w] = s;
  __syncthreads();
  if (t == 0) out_loss[0] = (red[0] + red[1] + red[2] + red[3]) * (1.0f / 2097152.0f);
}

extern "C" void kernel_launch(void* const* d_in, const int* in_sizes, int n_in,
                              void* d_out, int out_size, void* d_ws, size_t ws_size,
                              hipStream_t stream) {
  const float* x = (const float*)d_in[0];
  const float* E = (const float*)d_in[1];

  float* ws   = (float*)d_ws;
  float* Et   = ws + WS_ET;
  float* h    = ws + WS_H;
  float* part = ws + WS_PART;
  _Float16* Ehi = (_Float16*)(ws + WS_EHI);
  _Float16* Elo = (_Float16*)(ws + WS_ELO);

  float* out      = (float*)d_out;
  float* out_q    = out;                      // 2097152
  float* out_enc  = out + 2097152;            // 33554432
  float* out_ind  = out + 35651584;           // 32768
  float* out_loss = out + 35684352;           // 1

  kA_prep<<<16, 64, 0, stream>>>(E, Et, h, Ehi, Elo);
  kB_main<<<2048, 256, 0, stream>>>(x, Ehi, Elo, Et, h, part, out_q, out_enc, out_ind);
  k5_loss<<<1, 256, 0, stream>>>(part, out_loss);
}

// Round 14
// 233.854 us; speedup vs baseline: 1.0275x; 1.0005x over previous
//
#include <hip/hip_runtime.h>
#include <hip/hip_bf16.h>

// Problem: B=8, T=4096, D=64, K=1024. N = B*T = 32768 rows.
// Inputs:  d_in[0] = x (f32, 2097152), d_in[1] = embeddings (f32, [D][K])
// Output (f32): quantized (2097152) | encodings (33554432) | indices (32768) | loss (1)
//
// Score s[n,k] = x_n.e_k - 0.5||e_k||^2 (argmax == argmin distance).
// Split-fp16 3-MFMA coarse scores (err ~1e-4); near-ties (gap <= MARGIN)
// rescanned exactly in f32. r14: encodings ZEROS streamed by a dedicated
// fill-shaped kernel (no score dependency); scores write only ibest; ones
// scattered in the finalize kernel.

#define NROWS 32768
#define DDIM  64
#define KCB   1024
#define MARGIN 0.02f

typedef float    f32x4 __attribute__((ext_vector_type(4)));
typedef _Float16 f16x8 __attribute__((ext_vector_type(8)));

// ws layout (f32 index):
#define WS_ET    0         // Et f32 [k][64]             (65536)
#define WS_H     65536     // 0.5*||e_k||^2              (1024)
#define WS_PART  66560     // loss partials              (2048)
#define WS_IBEST 68608     // final index per row (int)  (32768)
#define WS_EHI   101376    // E hi fp16 permuted [k][64] (32768 f32 slots)
#define WS_ELO   134144    // E lo fp16 permuted [k][64] (32768 f32 slots)
// end: 166912 f32 = 668 KB

// K_A: Et f32 [k][d]; permuted split-fp16 Ehi/Elo (packed 16-B stores); h.
// slot p (0..31) of window w holds d = w*32 + 4*(p>>3) + (p&3) + 16*((p>>2)&1).
__global__ __launch_bounds__(64) void kA_prep(const float* __restrict__ E,
                                              float* __restrict__ Et,
                                              float* __restrict__ h,
                                              _Float16* __restrict__ Ehi,
                                              _Float16* __restrict__ Elo) {
  int k = blockIdx.x * 64 + threadIdx.x;    // 0..1023
  float col[DDIM];
  float sum = 0.f;
#pragma unroll
  for (int d = 0; d < DDIM; ++d) {
    float v = E[d * KCB + k];               // coalesced across lanes
    col[d] = v;
    sum = fmaf(v, v, sum);
  }
  float4* dst = (float4*)(Et + (size_t)k * DDIM);
#pragma unroll
  for (int i = 0; i < 16; ++i)
    dst[i] = make_float4(col[4*i], col[4*i+1], col[4*i+2], col[4*i+3]);
  h[k] = 0.5f * sum;

#pragma unroll
  for (int w = 0; w < 2; ++w) {
    f16x8 hi8[4], lo8[4];
#pragma unroll
    for (int p = 0; p < 32; ++p) {
      int dl = w * 32 + 4 * (p >> 3) + (p & 3) + 16 * ((p >> 2) & 1);
      float v = col[dl];
      _Float16 hi = (_Float16)v;
      hi8[p >> 3][p & 7] = hi;
      lo8[p >> 3][p & 7] = (_Float16)(v - (float)hi);
    }
#pragma unroll
    for (int q = 0; q < 4; ++q) {
      *(f16x8*)(Ehi + (size_t)k * DDIM + w * 32 + q * 8) = hi8[q];
      *(f16x8*)(Elo + (size_t)k * DDIM + w * 32 + q * 8) = lo8[q];
    }
  }
}

// K_Z: stream 134 MB of zeros into out_enc (the score-independent 94% of
// output bytes). Same shape as the 6.4 TB/s fill kernel: grid-stride f32x4.
__global__ __launch_bounds__(256) void kZ_zero(float* __restrict__ out_enc) {
  size_t t = (size_t)blockIdx.x * 256 + threadIdx.x;   // 0..524287
  f32x4* p = (f32x4*)out_enc;
  f32x4 z = (f32x4)(0.f);
#pragma unroll
  for (int i = 0; i < 16; ++i)
    p[t + (size_t)i * 524288] = z;                     // contiguous 8MB sweeps
}

// K_B: score+argmax only. Block = 256 thr (4 waves) = 32 rows (2 rowgroups);
// wave wq scores the 256-code quarter. 12 MFMAs per 4 E-loads.
__global__ __launch_bounds__(256, 4) void kB_score(const float* __restrict__ x,
                                                   const _Float16* __restrict__ Ehi,
                                                   const _Float16* __restrict__ Elo,
                                                   const float* __restrict__ Et,
                                                   const float* __restrict__ h,
                                                   int* __restrict__ ibest) {
  __shared__ float mb1[4][32], mb2[4][32];
  __shared__ int   mi1[4][32];
  __shared__ int   sidx[32];
  __shared__ int   flags[32];
  __shared__ int   nflag;
  __shared__ float rbw[4];
  __shared__ int   riw[4];

  int tid  = threadIdx.x;
  int wq   = tid >> 6;               // wave -> code quarter
  int lane = tid & 63;
  int g = lane >> 4, c = lane & 15;
  int r0 = blockIdx.x * 32;

  if (tid == 0) nflag = 0;

  // A-fragments for rows r0 + rg*16 + c; slots (g,e): d = w*32+4g+(e&3)+16*(e>>2)
  f16x8 Ahi[2][2], Alo[2][2];        // [rowgroup][window]
#pragma unroll
  for (int rg = 0; rg < 2; ++rg) {
    const float* xb = x + (size_t)(r0 + rg * 16 + c) * DDIM;
#pragma unroll
    for (int w = 0; w < 2; ++w) {
      f32x4 xa = *(const f32x4*)(xb + w * 32 + 4 * g);
      f32x4 xc = *(const f32x4*)(xb + w * 32 + 16 + 4 * g);
#pragma unroll
      for (int e = 0; e < 4; ++e) {
        _Float16 hi = (_Float16)xa[e];
        Ahi[rg][w][e] = hi;
        Alo[rg][w][e] = (_Float16)(xa[e] - (float)hi);
      }
#pragma unroll
      for (int e = 0; e < 4; ++e) {
        _Float16 hi = (_Float16)xc[e];
        Ahi[rg][w][4 + e] = hi;
        Alo[rg][w][4 + e] = (_Float16)(xc[e] - (float)hi);
      }
    }
  }

  float b1[2][4], b2[2][4];
  int   i1[2][4];
#pragma unroll
  for (int rg = 0; rg < 2; ++rg)
#pragma unroll
    for (int q = 0; q < 4; ++q) { b1[rg][q] = -3.0e38f; b2[rg][q] = -3.0e38f; i1[rg][q] = 0; }

  const _Float16* peh = Ehi + (size_t)(wq * 256 + c) * DDIM + g * 8;
  const _Float16* pel = Elo + (size_t)(wq * 256 + c) * DDIM + g * 8;

  f16x8 bh0n = *(const f16x8*)(peh);
  f16x8 bl0n = *(const f16x8*)(pel);
  f16x8 bh1n = *(const f16x8*)(peh + 32);
  f16x8 bl1n = *(const f16x8*)(pel + 32);
  float hn = h[wq * 256 + c];

#pragma unroll 1
  for (int ch = 0; ch < 16; ++ch) {
    f16x8 bh0 = bh0n, bl0 = bl0n, bh1 = bh1n, bl1 = bl1n;
    float hc = hn;
    if (ch < 15) {
      size_t off = (size_t)(ch + 1) * 16 * DDIM;
      bh0n = *(const f16x8*)(peh + off);
      bl0n = *(const f16x8*)(pel + off);
      bh1n = *(const f16x8*)(peh + off + 32);
      bl1n = *(const f16x8*)(pel + off + 32);
      hn = h[wq * 256 + (ch + 1) * 16 + c];
    }
    int code = wq * 256 + ch * 16 + c;
#pragma unroll
    for (int rg = 0; rg < 2; ++rg) {
      f32x4 a = { -hc, -hc, -hc, -hc };
      a = __builtin_amdgcn_mfma_f32_16x16x32_f16(Alo[rg][0], bh0, a, 0, 0, 0);
      a = __builtin_amdgcn_mfma_f32_16x16x32_f16(Ahi[rg][0], bl0, a, 0, 0, 0);
      a = __builtin_amdgcn_mfma_f32_16x16x32_f16(Ahi[rg][0], bh0, a, 0, 0, 0);
      a = __builtin_amdgcn_mfma_f32_16x16x32_f16(Alo[rg][1], bh1, a, 0, 0, 0);
      a = __builtin_amdgcn_mfma_f32_16x16x32_f16(Ahi[rg][1], bl1, a, 0, 0, 0);
      a = __builtin_amdgcn_mfma_f32_16x16x32_f16(Ahi[rg][1], bh1, a, 0, 0, 0);
#pragma unroll
      for (int q = 0; q < 4; ++q) {
        float s = a[q];
        bool gt = s > b1[rg][q];
        b2[rg][q] = gt ? b1[rg][q] : fmaxf(b2[rg][q], s);
        i1[rg][q] = gt ? code : i1[rg][q];
        b1[rg][q] = gt ? s : b1[rg][q];
      }
    }
  }

  // reduce across the 16 code-lanes (same g), lex tie-break to smaller index
#pragma unroll
  for (int step = 1; step <= 8; step <<= 1) {
#pragma unroll
    for (int rg = 0; rg < 2; ++rg)
#pragma unroll
      for (int q = 0; q < 4; ++q) {
        float ob1 = __shfl_xor(b1[rg][q], step);
        int   oi1 = __shfl_xor(i1[rg][q], step);
        float ob2 = __shfl_xor(b2[rg][q], step);
        bool win = (ob1 > b1[rg][q]) || (ob1 == b1[rg][q] && oi1 < i1[rg][q]);
        float loser = win ? b1[rg][q] : ob1;
        b1[rg][q] = win ? ob1 : b1[rg][q];
        i1[rg][q] = win ? oi1 : i1[rg][q];
        b2[rg][q] = fmaxf(fmaxf(b2[rg][q], ob2), loser);
      }
  }
  if (c == 0) {
#pragma unroll
    for (int rg = 0; rg < 2; ++rg)
#pragma unroll
      for (int q = 0; q < 4; ++q) {
        int row = rg * 16 + 4 * g + q;   // 0..31
        mb1[wq][row] = b1[rg][q];
        mi1[wq][row] = i1[rg][q];
        mb2[wq][row] = b2[rg][q];
      }
  }
  __syncthreads();

  // merge the 4 quarters (ascending -> first-occurrence ties); flag near-ties
  if (tid < 32) {
    float bb1 = mb1[0][tid], bb2 = mb2[0][tid];
    int   ii1 = mi1[0][tid];
#pragma unroll
    for (int qd = 1; qd < 4; ++qd) {
      float a1 = mb1[qd][tid];
      int   j1 = mi1[qd][tid];
      bool w1 = (a1 > bb1) || (a1 == bb1 && j1 < ii1);
      bb2 = fmaxf(fmaxf(bb2, mb2[qd][tid]), w1 ? bb1 : a1);
      bb1 = w1 ? a1 : bb1;
      ii1 = w1 ? j1 : ii1;
    }
    sidx[tid] = ii1;
    if (bb1 - bb2 <= MARGIN) { int p = atomicAdd(&nflag, 1); flags[p] = tid; }
  }
  __syncthreads();

  // exact f32 rescan of flagged rows (rare), whole block per row
  int nf = nflag;
#pragma unroll 1
  for (int fi = 0; fi < nf; ++fi) {
    int row = flags[fi];
    int n = r0 + row;
    const f32x4* xr = (const f32x4*)(x + (size_t)n * DDIM);   // L1/L2 broadcast
    float best = -3.0e38f; int bi = 0;
#pragma unroll 1
    for (int j = 0; j < 4; ++j) {
      int code = j * 256 + tid;
      const f32x4* er = (const f32x4*)(Et + (size_t)code * DDIM);
      float acc = -h[code];
#pragma unroll
      for (int d = 0; d < 16; ++d) {
        f32x4 e4 = er[d], x4 = xr[d];
        acc = fmaf(x4[0], e4[0], acc); acc = fmaf(x4[1], e4[1], acc);
        acc = fmaf(x4[2], e4[2], acc); acc = fmaf(x4[3], e4[3], acc);
      }
      if (acc > best || (acc == best && code < bi)) { best = acc; bi = code; }
    }
#pragma unroll
    for (int step = 1; step <= 32; step <<= 1) {
      float ob = __shfl_xor(best, step);
      int   oi = __shfl_xor(bi, step);
      if (ob > best || (ob == best && oi < bi)) { best = ob; bi = oi; }
    }
    if (lane == 0) { rbw[wq] = best; riw[wq] = bi; }
    __syncthreads();
    if (tid == 0) {
      float bb = rbw[0]; int ii = riw[0];
#pragma unroll
      for (int qd = 1; qd < 4; ++qd) {
        bool w1 = (rbw[qd] > bb) || (rbw[qd] == bb && riw[qd] < ii);
        bb = w1 ? rbw[qd] : bb;
        ii = w1 ? riw[qd] : ii;
      }
      sidx[row] = ii;
    }
    __syncthreads();
  }

  if (tid < 32) ibest[r0 + tid] = sidx[tid];
}

// K_C: finalize. 16 rows/block: indices, quantized gather (1 f32x4/thread),
// scatter the one-hot 1.0f's, loss partial.
__global__ __launch_bounds__(256) void kC_fin(const float* __restrict__ x,
                                              const float* __restrict__ Et,
                                              const int* __restrict__ ibest,
                                              float* __restrict__ partial,
                                              float* __restrict__ out_q,
                                              float* __restrict__ out_enc,
                                              float* __restrict__ out_ind) {
  __shared__ int sidx[16];
  int tid = threadIdx.x;
  int r0 = blockIdx.x * 16;

  if (tid < 16) {
    int n = r0 + tid;
    int bi = ibest[n];
    sidx[tid] = bi;
    out_ind[n] = (float)bi;
    out_enc[(size_t)n * KCB + bi] = 1.0f;     // scattered one per row
  }
  __syncthreads();

  // quantized + loss: 256 f32x4 chunks, 1 per thread (16 rows x 16 chunks)
  float lsum;
  {
    int row = tid >> 4, cc = tid & 15;
    int n = r0 + row;
    int bi = sidx[row];
    f32x4 q4 = *(const f32x4*)(Et + (size_t)bi * DDIM + cc * 4);
    f32x4 x4 = *(const f32x4*)(x + (size_t)n * DDIM + cc * 4);
    float d0 = q4[0] - x4[0], d1 = q4[1] - x4[1], d2 = q4[2] - x4[2], d3 = q4[3] - x4[3];
    lsum = d0 * d0;
    lsum = fmaf(d1, d1, lsum); lsum = fmaf(d2, d2, lsum); lsum = fmaf(d3, d3, lsum);
    *(f32x4*)(out_q + (size_t)n * DDIM + cc * 4) = q4;
  }

#pragma unroll
  for (int off = 32; off > 0; off >>= 1) lsum += __shfl_down(lsum, off);
  __shared__ float red[4];
  int lane = tid & 63, w = tid >> 6;
  if (lane == 0) red[w] = lsum;
  __syncthreads();
  if (tid == 0) partial[blockIdx.x] = red[0] + red[1] + red[2] + red[3];
}

// K5: reduce 2048 partials -> loss.
__global__ void k5_loss(const float* __restrict__ partial, float* __restrict__ out_loss) {
  int t = threadIdx.x;                 // 256 threads
  float s = 0.f;
#pragma unroll
  for (int i = 0; i < 8; ++i) s += partial[t + i * 256];
#pragma unroll
  for (int off = 32; off > 0; off >>= 1) s += __shfl_down(s, off);
  __shared__ float red[4];
  int lane = t & 63, w = t >> 6;
  if (lane == 0) red[w] = s;
  __syncthreads();
  if (t == 0) out_loss[0] = (red[0] + red[1] + red[2] + red[3]) * (1.0f / 2097152.0f);
}

extern "C" void kernel_launch(void* const* d_in, const int* in_sizes, int n_in,
                              void* d_out, int out_size, void* d_ws, size_t ws_size,
                              hipStream_t stream) {
  const float* x = (const float*)d_in[0];
  const float* E = (const float*)d_in[1];

  float* ws   = (float*)d_ws;
  float* Et   = ws + WS_ET;
  float* h    = ws + WS_H;
  float* part = ws + WS_PART;
  int*   ibest = (int*)(ws + WS_IBEST);
  _Float16* Ehi = (_Float16*)(ws + WS_EHI);
  _Float16* Elo = (_Float16*)(ws + WS_ELO);

  float* out      = (float*)d_out;
  float* out_q    = out;                      // 2097152
  float* out_enc  = out + 2097152;            // 33554432
  float* out_ind  = out + 35651584;           // 32768
  float* out_loss = out + 35684352;           // 1

  kA_prep<<<16, 64, 0, stream>>>(E, Et, h, Ehi, Elo);
  kZ_zero<<<2048, 256, 0, stream>>>(out_enc);
  kB_score<<<1024, 256, 0, stream>>>(x, Ehi, Elo, Et, h, ibest);
  kC_fin<<<2048, 256, 0, stream>>>(x, Et, ibest, part, out_q, out_enc, out_ind);
  k5_loss<<<1, 256, 0, stream>>>(part, out_loss);
}